// Round 1
// baseline (134.763 us; speedup 1.0000x reference)
//
#include <hip/hip_runtime.h>

// Problem constants (match reference).
#define CDIM 4096   // num_class
#define DDIM 512    // dim_label_emb
#define NWBLK 16    // w-compute blocks in kernel A (256 cols each)

// Math: mask = (u > 0.2f) ? 1.25f : 0.f; cumprod along rows => column j
// contributes co[k,j] * 1.25^(k+1) until the FIRST row k with u[k,j] <= 0.2,
// then exactly 0 forever. scale *= 1.25f reproduces jnp.cumprod's f32
// rounding exactly -> absmax 0. Accumulation order over k kept identical
// to the verified kernel.
//
// Restructure vs previous round: the 8 MB copy does NOT depend on w, so it
// no longer waits behind the w scan. Kernel A runs w-compute (16 blocks,
// dispatched first) concurrently with the copy (512 blocks); the w latency
// chain hides under the copy's BW phase. Kernel B does the dot only,
// re-reading label_emb from L2/LLC (just touched by A). Zero cross-block
// sync (graph edge orders A -> B) — rounds 2/3 of the prior session proved
// any cross-block wait costs 40-60 us here.

__global__ __launch_bounds__(256) void w_copy_kernel(
        const float* __restrict__ co, const float* __restrict__ mu,
        const float* __restrict__ emb, float* __restrict__ out,
        float* __restrict__ w) {
    const int bid = blockIdx.x;
    const int tid = threadIdx.x;
    if (bid < NWBLK) {
        // w for 256 columns: 4 independent waves, 64 cols each, per-wave
        // ballot early-exit (expected ~2 rounds of 16 rows).
        const int j = bid * 256 + tid;
        float acc = 0.f, scale = 1.25f;   // scale = 1.25^(k+1) at row k
        bool alive = true;
        for (int k0 = 0; k0 < CDIM; k0 += 16) {   // 32 loads in flight
            float u[16], c[16];
#pragma unroll
            for (int i = 0; i < 16; ++i) {
                size_t off = (size_t)(k0 + i) * CDIM + j;
                u[i] = mu[off];
                c[i] = co[off];
            }
#pragma unroll
            for (int i = 0; i < 16; ++i) {
                if (alive) {
                    if (u[i] > 0.2f) { acc += c[i] * scale; scale *= 1.25f; }
                    else             { alive = false; }
                }
            }
            if (__ballot(alive) == 0ULL) break;   // all 64 cols of wave dead
        }
        w[j] = acc;
    } else {
        // Pass-through copy of one emb row (output 0). Coalesced float4.
        const int d = bid - NWBLK;
        const float4* row  = (const float4*)(emb + (size_t)d * CDIM);
        float4*       orow = (float4*)(out + (size_t)d * CDIM);
#pragma unroll
        for (int it = 0; it < (CDIM / 4) / 256; ++it) {   // 4 iters
            int i = it * 256 + tid;
            orow[i] = row[i];
        }
    }
}

// Kernel B: block per row, dot vs w. Reduction structure bit-identical to
// the previously verified fused kernel (same element->thread mapping, same
// shfl tree, same part[] sum) -> absmax 0 preserved. emb read is L2/LLC-hot.
__global__ __launch_bounds__(256) void dot_kernel(
        const float* __restrict__ emb, const float* __restrict__ w,
        float* __restrict__ out) {
    const int d = blockIdx.x;
    const int tid = threadIdx.x;
    const float4* row = (const float4*)(emb + (size_t)d * CDIM);
    const float4* w4  = (const float4*)w;
    float acc = 0.f;
#pragma unroll
    for (int it = 0; it < (CDIM / 4) / 256; ++it) {   // 4 iters
        int i = it * 256 + tid;
        float4 v  = row[i];
        float4 ww = w4[i];
        acc += v.x * ww.x + v.y * ww.y + v.z * ww.z + v.w * ww.w;
    }
#pragma unroll
    for (int off = 32; off > 0; off >>= 1) acc += __shfl_down(acc, off, 64);
    __shared__ float part[4];
    int lane = tid & 63, wv = tid >> 6;
    if (lane == 0) part[wv] = acc;
    __syncthreads();
    if (tid == 0)
        out[(size_t)DDIM * CDIM + d] = part[0] + part[1] + part[2] + part[3];
}

extern "C" void kernel_launch(void* const* d_in, const int* in_sizes, int n_in,
                              void* d_out, int out_size, void* d_ws, size_t ws_size,
                              hipStream_t stream) {
    const float* label_emb = (const float*)d_in[0];   // (D, C)
    const float* co        = (const float*)d_in[1];   // (C, C)
    const float* mu        = (const float*)d_in[2];   // (C, C)
    float* out = (float*)d_out;                       // [D*C copy | D dim_emb]
    float* w   = (float*)d_ws;                        // C floats scratch

    w_copy_kernel<<<NWBLK + DDIM, 256, 0, stream>>>(co, mu, label_emb, out, w);
    dot_kernel<<<DDIM, 256, 0, stream>>>(label_emb, w, out);
}

// Round 2
// 132.309 us; speedup vs baseline: 1.0186x; 1.0186x over previous
//
#include <hip/hip_runtime.h>

// Problem constants (match reference).
#define CDIM 4096   // num_class
#define DDIM 512    // dim_label_emb

// Math: mask = (u > 0.2f) ? 1.25f : 0.f; cumprod along rows => column j
// contributes co[k,j] * 1.25^(k+1) until the FIRST row k with u[k,j] <= 0.2,
// then exactly 0 forever. scale *= 1.25f reproduces jnp.cumprod's f32
// rounding exactly (mask values are exactly {0, 1.25f}) -> absmax 0.
//
// Two kernels, zero inter-block sync (graph edge orders them):
//  - Prior session rounds 2/3: ANY cross-block wait costs 40-60 us here.
//  - Prior session round 4: producer-side lane-per-row dot is a scatter;
//    block-per-row coalesced dot (K2) is the right shape.
//  - This session round 1: overlapping the copy with the w-scan REGRESSES
//    (+2.8 us) — copy BW contention stretches w's latency-bound chain, and
//    de-fusing copy+dot costs a second emb read. Keep w alone (idle-machine
//    latency), keep copy+dot fused (single emb pass).

// K1: w[j] for 64 columns per block, one wave per block -> 64 CUs in
// parallel, ballot early-exit at wave granularity (expected ~2 rounds of 16).
__global__ __launch_bounds__(64) void w_kernel(
        const float* __restrict__ co, const float* __restrict__ mu,
        float* __restrict__ w) {
    const int j = blockIdx.x * 64 + threadIdx.x;
    float acc = 0.f, scale = 1.25f;   // scale = 1.25^(k+1) at row k
    bool alive = true;
    for (int k0 = 0; k0 < CDIM; k0 += 16) {   // 32 loads in flight
        float u[16], c[16];
#pragma unroll
        for (int i = 0; i < 16; ++i) {
            size_t off = (size_t)(k0 + i) * CDIM + j;
            u[i] = mu[off];
            c[i] = co[off];
        }
#pragma unroll
        for (int i = 0; i < 16; ++i) {
            if (alive) {
                if (u[i] > 0.2f) { acc += c[i] * scale; scale *= 1.25f; }
                else             { alive = false; }
            }
        }
        if (__ballot(alive) == 0ULL) break;   // all 64 cols of this wave dead
    }
    w[j] = acc;
}

// K2: block per row — coalesced float4 read of the row (once), write the
// copy (output 0), accumulate dot vs w, wave+LDS reduce -> out1[d].
__global__ __launch_bounds__(256) void dot_copy_kernel(
        const float* __restrict__ emb, const float* __restrict__ w,
        float* __restrict__ out) {
    const int d = blockIdx.x;
    const int tid = threadIdx.x;
    const float4* row  = (const float4*)(emb + (size_t)d * CDIM);
    float4*       orow = (float4*)(out + (size_t)d * CDIM);
    const float4* w4   = (const float4*)w;
    float acc = 0.f;
#pragma unroll
    for (int it = 0; it < (CDIM / 4) / 256; ++it) {   // 4 iters
        int i = it * 256 + tid;
        float4 v  = row[i];
        float4 ww = w4[i];
        orow[i] = v;                       // output 0: pass-through copy
        acc += v.x * ww.x + v.y * ww.y + v.z * ww.z + v.w * ww.w;
    }
#pragma unroll
    for (int off = 32; off > 0; off >>= 1) acc += __shfl_down(acc, off, 64);
    __shared__ float part[4];
    int lane = tid & 63, wv = tid >> 6;
    if (lane == 0) part[wv] = acc;
    __syncthreads();
    if (tid == 0)
        out[(size_t)DDIM * CDIM + d] = part[0] + part[1] + part[2] + part[3];
}

extern "C" void kernel_launch(void* const* d_in, const int* in_sizes, int n_in,
                              void* d_out, int out_size, void* d_ws, size_t ws_size,
                              hipStream_t stream) {
    const float* label_emb = (const float*)d_in[0];   // (D, C)
    const float* co        = (const float*)d_in[1];   // (C, C)
    const float* mu        = (const float*)d_in[2];   // (C, C)
    float* out = (float*)d_out;                       // [D*C copy | D dim_emb]
    float* w   = (float*)d_ws;                        // C floats scratch

    w_kernel<<<CDIM / 64, 64, 0, stream>>>(co, mu, w);
    dot_copy_kernel<<<DDIM, 256, 0, stream>>>(label_emb, w, out);
}